// Round 1
// baseline (125.014 us; speedup 1.0000x reference)
//
#include <hip/hip_runtime.h>
#include <hip/hip_bf16.h>

#define NQ 6
#define DIM 64
#define NLAYERS 6

// ---------------------------------------------------------------------------
// Setup: build the fused circuit matrix M = P*U5*P*U4*...*P*U0*F (complex 64x64)
// Mr/Mi written to workspace (each 64*64 floats).
// ---------------------------------------------------------------------------
__global__ void build_M(const float* __restrict__ w,
                        float* __restrict__ Mr_g, float* __restrict__ Mi_g) {
    __shared__ float Mr[DIM][DIM];
    __shared__ float Mi[DIM][DIM];
    const int tid = threadIdx.x;           // 512 threads
    // ---- QFT init: F[j][k] = exp(2*pi*i*j*k/64)/8
    for (int idx = tid; idx < DIM * DIM; idx += 512) {
        int j = idx >> 6, k = idx & 63;
        int t = (j * k) & 63;
        float sv, cv;
        sincospif((float)t / 32.0f, &sv, &cv);   // exp(i*pi*(t/32))
        Mr[j][k] = cv * 0.125f;
        Mi[j][k] = sv * 0.125f;
    }
    __syncthreads();

    for (int l = 0; l < NLAYERS; ++l) {
        // ---- RY layer: per-qubit row-pair rotation, qubit q acts on bit (5-q)
        for (int q = 0; q < NQ; ++q) {
            float th = w[l * NQ + q] * 0.5f;
            float c = cosf(th), s = sinf(th);
            int b = 5 - q;
            int mask = (1 << b) - 1;
            // 32 pairs x 64 cols = 2048 items
            for (int item = tid; item < 2048; item += 512) {
                int pr = item >> 6, k = item & 63;
                int i0 = ((pr & ~mask) << 1) | (pr & mask);
                int i1 = i0 | (1 << b);
                float r0 = Mr[i0][k], p0 = Mi[i0][k];
                float r1 = Mr[i1][k], p1 = Mi[i1][k];
                Mr[i0][k] = c * r0 - s * r1;  Mi[i0][k] = c * p0 - s * p1;
                Mr[i1][k] = s * r0 + c * r1;  Mi[i1][k] = s * p0 + c * p1;
            }
            __syncthreads();
        }
        // ---- CNOT ring permutation: newM[f(row)] = M[row]
        float vr[8], vi[8];
        int dst[8];
#pragma unroll
        for (int e = 0; e < 8; ++e) {
            int idx = tid + e * 512;
            int row = idx >> 6;
            int m = row;
#pragma unroll
            for (int q = 0; q < NQ; ++q) {
                int cb = 5 - q;
                int tb = 5 - ((q + 1) % NQ);
                if ((m >> cb) & 1) m ^= (1 << tb);
            }
            vr[e] = Mr[row][idx & 63];
            vi[e] = Mi[row][idx & 63];
            dst[e] = m;
        }
        __syncthreads();
#pragma unroll
        for (int e = 0; e < 8; ++e) {
            int idx = tid + e * 512;
            Mr[dst[e]][idx & 63] = vr[e];
            Mi[dst[e]][idx & 63] = vi[e];
        }
        __syncthreads();
    }

    for (int idx = tid; idx < DIM * DIM; idx += 512) {
        Mr_g[idx] = (&Mr[0][0])[idx];
        Mi_g[idx] = (&Mi[0][0])[idx];
    }
}

// ---------------------------------------------------------------------------
// Main: one thread per batch row.  out[b][j] = (yr^2 + yi^2)/||x||^2,
// y = M @ x.  x row lives in 64 VGPRs; M reads are wave-uniform (s_load).
// ---------------------------------------------------------------------------
__global__ __launch_bounds__(256) void qenc_main(const float* __restrict__ x,
                                                 const float* __restrict__ Mr,
                                                 const float* __restrict__ Mi,
                                                 float* __restrict__ out, int B) {
    int row = blockIdx.x * blockDim.x + threadIdx.x;
    if (row >= B) return;
    const float4* xr = (const float4*)(x + (size_t)row * DIM);
    float xv[DIM];
    float n2 = 0.0f;
#pragma unroll
    for (int c = 0; c < 16; ++c) {
        float4 v = xr[c];
        xv[4 * c + 0] = v.x; xv[4 * c + 1] = v.y;
        xv[4 * c + 2] = v.z; xv[4 * c + 3] = v.w;
        n2 += v.x * v.x + v.y * v.y + v.z * v.z + v.w * v.w;
    }
    float inv = 1.0f / n2;
    float4* orow = (float4*)(out + (size_t)row * DIM);
#pragma unroll 1
    for (int j0 = 0; j0 < DIM; j0 += 4) {
        const float* mr = Mr + j0 * DIM;
        const float* mi = Mi + j0 * DIM;
        float ar0 = 0.f, ai0 = 0.f, ar1 = 0.f, ai1 = 0.f;
        float ar2 = 0.f, ai2 = 0.f, ar3 = 0.f, ai3 = 0.f;
#pragma unroll
        for (int k = 0; k < DIM; ++k) {
            float xk = xv[k];
            ar0 = fmaf(mr[k], xk, ar0);
            ai0 = fmaf(mi[k], xk, ai0);
            ar1 = fmaf(mr[DIM + k], xk, ar1);
            ai1 = fmaf(mi[DIM + k], xk, ai1);
            ar2 = fmaf(mr[2 * DIM + k], xk, ar2);
            ai2 = fmaf(mi[2 * DIM + k], xk, ai2);
            ar3 = fmaf(mr[3 * DIM + k], xk, ar3);
            ai3 = fmaf(mi[3 * DIM + k], xk, ai3);
        }
        float4 o;
        o.x = (ar0 * ar0 + ai0 * ai0) * inv;
        o.y = (ar1 * ar1 + ai1 * ai1) * inv;
        o.z = (ar2 * ar2 + ai2 * ai2) * inv;
        o.w = (ar3 * ar3 + ai3 * ai3) * inv;
        orow[j0 >> 2] = o;
    }
}

extern "C" void kernel_launch(void* const* d_in, const int* in_sizes, int n_in,
                              void* d_out, int out_size, void* d_ws, size_t ws_size,
                              hipStream_t stream) {
    const float* x = (const float*)d_in[0];
    const float* w = (const float*)d_in[1];
    float* out = (float*)d_out;
    float* Mr = (float*)d_ws;              // 4096 floats
    float* Mi = Mr + DIM * DIM;            // 4096 floats
    int B = in_sizes[0] / DIM;

    hipLaunchKernelGGL(build_M, dim3(1), dim3(512), 0, stream, w, Mr, Mi);
    hipLaunchKernelGGL(qenc_main, dim3((B + 255) / 256), dim3(256), 0, stream,
                       x, Mr, Mi, out, B);
}

// Round 2
// 33.181 us; speedup vs baseline: 3.7677x; 3.7677x over previous
//
#include <hip/hip_runtime.h>
#include <hip/hip_bf16.h>

#define NQ 6
#define DIM 64
#define NLAYERS 6
#define PAD 68   // padded j-stride (floats): mult of 4 (b128 align), 68%32=4 breaks bank aliasing

// ---------------------------------------------------------------------------
// build_M: one block (=1 wave, 64 lanes) per QFT column k. Lane j carries
// M[j][k] through the circuit: RY layers via shfl_xor pair-rotations, CNOT
// ring via ds_permute push. Output written TRANSPOSED+PADDED: Mt[k*PAD + j]
// (real), Mt[64*PAD*1 + ...] wait -- real plane then imag plane.
// ---------------------------------------------------------------------------
__global__ __launch_bounds__(64) void build_M(const float* __restrict__ w,
                                              float* __restrict__ Mt) {
    const int k = blockIdx.x;    // column 0..63
    const int j = threadIdx.x;   // row/lane 0..63

    // F[j][k] = exp(i*pi*(jk mod 64)/32)/8
    int t = (j * k) & 63;
    float sv, cv;
    sincospif((float)t / 32.0f, &sv, &cv);
    float vr = cv * 0.125f;
    float vi = sv * 0.125f;

    // CNOT-ring composite destination lane (push index), same every layer
    int m = j;
#pragma unroll
    for (int q = 0; q < NQ; ++q) {
        int cb = 5 - q;
        int tb = 5 - ((q + 1) % NQ);
        if ((m >> cb) & 1) m ^= (1 << tb);
    }
    const int dst4 = m << 2;

    for (int l = 0; l < NLAYERS; ++l) {
#pragma unroll
        for (int q = 0; q < NQ; ++q) {
            float th = w[l * NQ + q] * 0.5f;
            float c = cosf(th), s = sinf(th);
            int b = 5 - q;
            float pr = __shfl_xor(vr, 1 << b);
            float pi = __shfl_xor(vi, 1 << b);
            float sgn = ((j >> b) & 1) ? s : -s;   // lo: c*own - s*par ; hi: c*own + s*par
            vr = c * vr + sgn * pr;
            vi = c * vi + sgn * pi;
        }
        // permutation: lane j pushes its value to lane m(j)
        vr = __int_as_float(__builtin_amdgcn_ds_permute(dst4, __float_as_int(vr)));
        vi = __int_as_float(__builtin_amdgcn_ds_permute(dst4, __float_as_int(vi)));
    }

    Mt[k * PAD + j] = vr;                 // real plane  [64][PAD]
    Mt[DIM * PAD + k * PAD + j] = vi;     // imag plane  [64][PAD]
}

// ---------------------------------------------------------------------------
// Main: block = 256 threads handles 64 rows. Thread (rg=t/16, jg=t%16)
// computes rows 4rg..4rg+3  x  outputs j=4jg..4jg+3.
// M in LDS as [k][jPAD] (from build_M, linear conflict-free copy);
// x in LDS as [row][kPAD]. All inner reads are ds_read_b128, <=2-way alias.
// ---------------------------------------------------------------------------
__global__ __launch_bounds__(256) void qenc_main(const float* __restrict__ x,
                                                 const float* __restrict__ Mt,
                                                 float* __restrict__ out, int B) {
    __shared__ float sM[2 * DIM * PAD];   // 34816 B
    __shared__ float sX[DIM * PAD];       // 17408 B
    const int tid = threadIdx.x;
    const int row0 = blockIdx.x * 64;

    for (int i = tid; i < 2 * DIM * PAD; i += 256) sM[i] = Mt[i];
    const float* xb = x + (size_t)row0 * DIM;
    for (int i = tid; i < 64 * DIM; i += 256) {
        int r = i >> 6, k = i & 63;
        sX[r * PAD + k] = xb[i];
    }
    __syncthreads();

    const int jg = tid & 15;
    const int rg = tid >> 4;
    const float* mr = sM + 4 * jg;               // + k*PAD
    const float* mi = sM + DIM * PAD + 4 * jg;   // + k*PAD
    const float* xr = sX + (4 * rg) * PAD;       // rows 4rg..4rg+3

    float accr[4][4] = {};   // [rr][jjj]
    float acci[4][4] = {};
    float nrm[4] = {0.f, 0.f, 0.f, 0.f};

#pragma unroll 2
    for (int k4 = 0; k4 < DIM; k4 += 4) {
        float4 xv[4];
#pragma unroll
        for (int rr = 0; rr < 4; ++rr)
            xv[rr] = *(const float4*)(xr + rr * PAD + k4);
#pragma unroll
        for (int kk = 0; kk < 4; ++kk) {
            const int k = k4 + kk;
            const float4 m_r = *(const float4*)(mr + k * PAD);
            const float4 m_i = *(const float4*)(mi + k * PAD);
#pragma unroll
            for (int rr = 0; rr < 4; ++rr) {
                const float xk = (&xv[rr].x)[kk];
                nrm[rr] = fmaf(xk, xk, nrm[rr]);
                accr[rr][0] = fmaf(m_r.x, xk, accr[rr][0]);
                accr[rr][1] = fmaf(m_r.y, xk, accr[rr][1]);
                accr[rr][2] = fmaf(m_r.z, xk, accr[rr][2]);
                accr[rr][3] = fmaf(m_r.w, xk, accr[rr][3]);
                acci[rr][0] = fmaf(m_i.x, xk, acci[rr][0]);
                acci[rr][1] = fmaf(m_i.y, xk, acci[rr][1]);
                acci[rr][2] = fmaf(m_i.z, xk, acci[rr][2]);
                acci[rr][3] = fmaf(m_i.w, xk, acci[rr][3]);
            }
        }
    }

#pragma unroll
    for (int rr = 0; rr < 4; ++rr) {
        const float inv = 1.0f / nrm[rr];   // norm redundantly computed per jg; exact fp32
        float4 o;
        o.x = (accr[rr][0] * accr[rr][0] + acci[rr][0] * acci[rr][0]) * inv;
        o.y = (accr[rr][1] * accr[rr][1] + acci[rr][1] * acci[rr][1]) * inv;
        o.z = (accr[rr][2] * accr[rr][2] + acci[rr][2] * acci[rr][2]) * inv;
        o.w = (accr[rr][3] * accr[rr][3] + acci[rr][3] * acci[rr][3]) * inv;
        *(float4*)(out + (size_t)(row0 + 4 * rg + rr) * DIM + 4 * jg) = o;
    }
}

extern "C" void kernel_launch(void* const* d_in, const int* in_sizes, int n_in,
                              void* d_out, int out_size, void* d_ws, size_t ws_size,
                              hipStream_t stream) {
    const float* x = (const float*)d_in[0];
    const float* w = (const float*)d_in[1];
    float* out = (float*)d_out;
    float* Mt = (float*)d_ws;   // [2][64][PAD] floats = 34816 B
    int B = in_sizes[0] / DIM;

    hipLaunchKernelGGL(build_M, dim3(DIM), dim3(64), 0, stream, w, Mt);
    hipLaunchKernelGGL(qenc_main, dim3(B / 64), dim3(256), 0, stream, x, Mt, out, B);
}

// Round 4
// 20.939 us; speedup vs baseline: 5.9703x; 1.5846x over previous
//
#include <hip/hip_runtime.h>
#include <hip/hip_bf16.h>

#define NQ 6
#define DIM 64
#define NLAYERS 6

typedef __attribute__((ext_vector_type(8))) short bf16x8;
typedef __attribute__((ext_vector_type(4))) float f32x4;

// ---------------------------------------------------------------------------
// build_M: fused circuit matrix M = P*U5*...*P*U0*F (complex 64x64), emitted
// directly as MFMA B-fragments in bf16 hi/lo split, frag-linear:
//   frag index f = (jt*2 + chunk)*4 + plane   (plane: 0=r_hi 1=r_lo 2=i_hi 3=i_lo)
//   ushort addr  = f*512 + lane16*8 + e
// where for element M[j][k]: jt=j>>4, lane16=(j&15)+16*((k>>3)&3), chunk=k>>5,
// e=k&7.  A-frags in qenc_main use the SAME (group,elem)->k mapping, so the
// MFMA positional pairing is consistent regardless of the HW's internal order.
// ---------------------------------------------------------------------------
__global__ __launch_bounds__(64) void build_M(const float* __restrict__ w,
                                              unsigned short* __restrict__ Bf) {
    const int k = blockIdx.x;    // column 0..63
    const int j = threadIdx.x;   // row/lane 0..63

    int t = (j * k) & 63;
    float sv, cv;
    sincospif((float)t / 32.0f, &sv, &cv);   // exp(i*pi*t/32)
    float vr = cv * 0.125f;
    float vi = sv * 0.125f;

    // CNOT-ring composite destination lane (push), same every layer
    int m = j;
#pragma unroll
    for (int q = 0; q < NQ; ++q) {
        int cb = 5 - q;
        int tb = 5 - ((q + 1) % NQ);
        if ((m >> cb) & 1) m ^= (1 << tb);
    }
    const int dst4 = m << 2;

    for (int l = 0; l < NLAYERS; ++l) {
#pragma unroll
        for (int q = 0; q < NQ; ++q) {
            float th = w[l * NQ + q] * 0.5f;
            float c = cosf(th), s = sinf(th);
            int b = 5 - q;
            float pr = __shfl_xor(vr, 1 << b);
            float pi = __shfl_xor(vi, 1 << b);
            float sgn = ((j >> b) & 1) ? s : -s;
            vr = c * vr + sgn * pr;
            vi = c * vi + sgn * pi;
        }
        vr = __int_as_float(__builtin_amdgcn_ds_permute(dst4, __float_as_int(vr)));
        vi = __int_as_float(__builtin_amdgcn_ds_permute(dst4, __float_as_int(vi)));
    }

    // bf16 hi/lo split and scatter into fragment layout (ushort units)
    const int jt = j >> 4;
    const int lane16 = (j & 15) + 16 * ((k >> 3) & 3);
    const int chunk = k >> 5;
    const int e = k & 7;
    const int base = ((jt * 2 + chunk) * 4) * 512 + lane16 * 8 + e;

    __hip_bfloat16 rh = __float2bfloat16(vr);
    __hip_bfloat16 rl = __float2bfloat16(vr - __bfloat162float(rh));
    __hip_bfloat16 ih = __float2bfloat16(vi);
    __hip_bfloat16 il = __float2bfloat16(vi - __bfloat162float(ih));
    Bf[base]        = *(unsigned short*)&rh;
    Bf[base + 512]  = *(unsigned short*)&rl;
    Bf[base + 1024] = *(unsigned short*)&ih;
    Bf[base + 1536] = *(unsigned short*)&il;
}

// ---------------------------------------------------------------------------
// qenc_main: 4 waves/block, each wave computes a 16-row x 64-col tile via
// mfma_f32_16x16x32_bf16 with hi/lo split (3 MFMA per r/i per K-chunk).
// M fragments staged once to LDS (32KB, conflict-free sequential reads).
// ---------------------------------------------------------------------------
__global__ __launch_bounds__(256) void qenc_main(const float* __restrict__ x,
                                                 const unsigned short* __restrict__ Bf,
                                                 float* __restrict__ out) {
    __shared__ __align__(16) unsigned short sB[16384];   // 32 KB
    const int tid = threadIdx.x;

    {   // linear stage: global -> LDS
        const float4* src = (const float4*)Bf;
        float4* dst = (float4*)sB;
#pragma unroll
        for (int i = 0; i < 8; ++i) dst[tid + 256 * i] = src[tid + 256 * i];
    }

    const int lane = tid & 63;
    const int wid = tid >> 6;
    const int row0 = blockIdx.x * 64 + wid * 16;
    const int r = lane & 15;      // A row within tile
    const int g = lane >> 4;      // k-group

    // A: 16 floats of row (row0+r): k = {8g..8g+7} and {32+8g..32+8g+7}
    const float* xp = x + (size_t)(row0 + r) * DIM + 8 * g;
    float xf[16];
    *(float4*)(xf)      = *(const float4*)(xp);
    *(float4*)(xf + 4)  = *(const float4*)(xp + 4);
    *(float4*)(xf + 8)  = *(const float4*)(xp + 32);
    *(float4*)(xf + 12) = *(const float4*)(xp + 36);

    // norm: per-row sum of squares (reduce over the 4 lanes sharing r)
    float p2 = 0.f;
#pragma unroll
    for (int i = 0; i < 16; ++i) p2 = fmaf(xf[i], xf[i], p2);
    p2 += __shfl_xor(p2, 16);
    p2 += __shfl_xor(p2, 32);
    const float inv = 1.0f / p2;   // valid on every lane, for row index r

    // hi/lo bf16 A-fragments
    bf16x8 ah[2], al[2];
#pragma unroll
    for (int c = 0; c < 2; ++c)
#pragma unroll
        for (int i = 0; i < 8; ++i) {
            float f = xf[c * 8 + i];
            __hip_bfloat16 h = __float2bfloat16(f);
            __hip_bfloat16 lo = __float2bfloat16(f - __bfloat162float(h));
            ah[c][i] = *(short*)&h;
            al[c][i] = *(short*)&lo;
        }

    __syncthreads();

    const f32x4 z = {0.f, 0.f, 0.f, 0.f};
    f32x4 acr[4] = {z, z, z, z};
    f32x4 aci[4] = {z, z, z, z};
    const unsigned short* bp = sB + lane * 8;

#pragma unroll
    for (int jt = 0; jt < 4; ++jt) {
#pragma unroll
        for (int c = 0; c < 2; ++c) {
            const unsigned short* fb = bp + ((jt * 2 + c) * 4) * 512;
            bf16x8 brh = *(const bf16x8*)(fb);
            bf16x8 brl = *(const bf16x8*)(fb + 512);
            bf16x8 bih = *(const bf16x8*)(fb + 1024);
            bf16x8 bil = *(const bf16x8*)(fb + 1536);
            acr[jt] = __builtin_amdgcn_mfma_f32_16x16x32_bf16(ah[c], brh, acr[jt], 0, 0, 0);
            acr[jt] = __builtin_amdgcn_mfma_f32_16x16x32_bf16(ah[c], brl, acr[jt], 0, 0, 0);
            acr[jt] = __builtin_amdgcn_mfma_f32_16x16x32_bf16(al[c], brh, acr[jt], 0, 0, 0);
            aci[jt] = __builtin_amdgcn_mfma_f32_16x16x32_bf16(ah[c], bih, aci[jt], 0, 0, 0);
            aci[jt] = __builtin_amdgcn_mfma_f32_16x16x32_bf16(ah[c], bil, aci[jt], 0, 0, 0);
            aci[jt] = __builtin_amdgcn_mfma_f32_16x16x32_bf16(al[c], bih, aci[jt], 0, 0, 0);
        }
    }

    // epilogue: C/D layout col=lane&15, row=4*(lane>>4)+reg  (HW-verified)
    float invv[4];
#pragma unroll
    for (int v = 0; v < 4; ++v) invv[v] = __shfl(inv, 4 * g + v);

    float* op = out + (size_t)(row0 + 4 * g) * DIM + r;
#pragma unroll
    for (int v = 0; v < 4; ++v)
#pragma unroll
        for (int jt = 0; jt < 4; ++jt) {
            float yr = acr[jt][v];
            float yi = aci[jt][v];
            op[(size_t)v * DIM + jt * 16] = (yr * yr + yi * yi) * invv[v];
        }
}

extern "C" void kernel_launch(void* const* d_in, const int* in_sizes, int n_in,
                              void* d_out, int out_size, void* d_ws, size_t ws_size,
                              hipStream_t stream) {
    const float* x = (const float*)d_in[0];
    const float* w = (const float*)d_in[1];
    float* out = (float*)d_out;
    unsigned short* Bf = (unsigned short*)d_ws;   // 32 KB fragment image
    int B = in_sizes[0] / DIM;

    hipLaunchKernelGGL(build_M, dim3(DIM), dim3(64), 0, stream, w, Bf);
    hipLaunchKernelGGL(qenc_main, dim3(B / 64), dim3(256), 0, stream, x, Bf, out);
}